// Round 3
// baseline (136.065 us; speedup 1.0000x reference)
//
#include <hip/hip_runtime.h>
#include <hip/hip_bf16.h>
#include <math.h>

#define INPUT_DIM 256
#define OUT_DIM   256
#define NDEG      8                    // degree+1
#define KTOT      (INPUT_DIM * NDEG)   // 2048
#define NROWS     (16 * 2048)          // 32768

#define BM  64                         // block rows (featurize exactly once globally)
#define BK  64                         // 8 inputs * 8 degrees per K-chunk
#define NK  (KTOT / BK)                // 32
#define SUPER 4                        // chunks per super-step (barrier granularity)
#define NSUP  (NK / SUPER)             // 8
#define CHUNK_ELEMS 16384              // full-width B chunk: 256 o * 64 k
#define APAGE 512                      // A page: 64 rows * 8 deg (one input)
#define ACHUNK (8 * APAGE)             // 4096 elems = 8 KB

typedef __bf16 bf16x8 __attribute__((ext_vector_type(8)));
typedef float  f32x16 __attribute__((ext_vector_type(16)));

// ---------------------------------------------------------------------------
// Kernel 1: reorder coeffs C[i][o][d] (fp32) -> B pages (bf16). Unchanged R9
// layout (row-tile independent): frag(kc,s,c,ni) at
//   kc*16384 + (s*4+c)*1024 + ni*512 + h*256 + l31*8 + d
// ---------------------------------------------------------------------------
__global__ __launch_bounds__(256) void reorder_coeffs(const float* __restrict__ C,
                                                      __bf16* __restrict__ Bt) {
    int g = blockIdx.x * 256 + threadIdx.x;   // 65536 = 256 i * 256 o
    int i = g >> 8;
    int o = g & 255;
    const float4* src = (const float4*)(C + (size_t)i * (OUT_DIM * NDEG) + o * NDEG);
    float4 a = src[0];
    float4 b = src[1];
    bf16x8 v;
    v[0] = (__bf16)a.x; v[1] = (__bf16)a.y; v[2] = (__bf16)a.z; v[3] = (__bf16)a.w;
    v[4] = (__bf16)b.x; v[5] = (__bf16)b.y; v[6] = (__bf16)b.z; v[7] = (__bf16)b.w;
    int kc = i >> 3;
    int p  = i & 7;
    int s  = p >> 1;
    int hh = p & 1;
    int cc = o >> 6;
    int ni = (o >> 5) & 1;
    int l31 = o & 255 & 31;
    l31 = o & 31;
    size_t dst = (size_t)kc * CHUNK_ELEMS + (s * 4 + cc) * 1024 + ni * 512 + hh * 256 + l31 * 8;
    *(bf16x8*)(Bt + dst) = v;   // 16B-aligned
}

// tanh + physicists' Hermite recurrence -> 8 degrees as bf16x8
__device__ __forceinline__ bf16x8 featurize(float xs) {
    float e = __expf(2.0f * xs);            // tanh(x)=1-2/(e^{2x}+1), robust all x
    float t = 1.0f - 2.0f / (e + 1.0f);
    bf16x8 v;
    float hm2 = 1.0f;                       // H_0
    float hm1 = 2.0f * t;                   // H_1
    v[0] = (__bf16)hm2;
    v[1] = (__bf16)hm1;
    #pragma unroll
    for (int d = 2; d < 8; ++d) {
        float h = 2.0f * t * hm1 - 2.0f * (float)(d - 1) * hm2;
        v[d] = (__bf16)h;
        hm2 = hm1; hm1 = h;
    }
    return v;
}

// lgkm-only barrier: each wave's own LDS writes/reads complete (lgkmcnt(0))
// before it signals -- full producer/consumer requirement for the Alds dbuf.
// B/x prefetch loads target registers and carry compiler vmcnt waits at use
// sites; they legally stay in flight across the barrier.
#define BARRIER() do {                                             \
    asm volatile("s_waitcnt lgkmcnt(0)" ::: "memory");             \
    __builtin_amdgcn_s_barrier();                                  \
    asm volatile("" ::: "memory");                                 \
} while (0)

// ---------------------------------------------------------------------------
// Kernel 2 (Round 12): phase decorrelation via 2 blocks/CU.
//  R11 post-mortem: one block/CU with per-block barriers keeps all 8 waves
//  phase-locked (2 phase-identical waves/SIMD), so MFMA(30%)+VALU(24%)+
//  LDS(~28%) stay ADDITIVE. Textual interleave can't fix an in-order wave;
//  overlap needs co-resident waves in DIFFERENT phases (m114).
//  Fix: BM=64, 512-thread blocks, grid 512 = 2 independent barrier groups
//  per CU, 4 waves/SIMD. When block A featurizes, block B runs MFMA.
//  - LDS 64 KB/block (SUPER=4 chunks x dbuf), both blocks fit in 160 KB.
//  - Wave tile 32x64 (acc = 32 AGPR), 2 mr x 4 c.
//  - B pages / reorder / reg-dbuf unchanged; A pages scale to 64 rows
//    (whole-wave 1 KB contiguous reads+writes: 0 bank conflicts).
//  - Cost: B-from-L2 doubles to 512 MB total (~30 B/cyc/CU, under ceiling).
// ---------------------------------------------------------------------------
__global__ __launch_bounds__(512, 4) void hermite_mfma(const float* __restrict__ x,
                                                       const __bf16* __restrict__ Bt,
                                                       float* __restrict__ out) {
    // [buf][(input-in-super)*512 + m*8]; input-in-super = chunk cc*8 + page j
    __shared__ __align__(16) __bf16 Alds[2][SUPER * ACHUNK];   // 64 KB

    const int tid  = threadIdx.x;
    const int bm   = blockIdx.x;       // 0..511
    const int wave = tid >> 6;         // 0..7
    const int mr   = wave >> 2;        // 0..1 : row half (32 rows each)
    const int c    = wave & 3;         // 0..3 : column slice
    const int lane = tid & 63;
    const int l31  = lane & 31;
    const int h    = lane >> 5;

    // Featurize mapping: thread (m = tid&63, pg = tid>>6) covers row m,
    // inputs sup*32 + pg*4 + {0..3} (one float4). Exactly-once globally.
    const int m  = tid & 63;
    const int pg = tid >> 6;           // 0..7
    const float* xptr = x + (size_t)(bm * BM + m) * INPUT_DIM + pg * 4;

    // B pages for column slice c: frag(kc,s,ni) at Bt + kc*16384 + (s*4+c)*1024
    //   + ni*512 + lane*8
    const __bf16* bbase = Bt + (size_t)c * 1024 + lane * 8;

    f32x16 acc[2] = {};
    bf16x8 bfr0[4][2];                 // chunk B-frag buffer A (static names)
    bf16x8 bfr1[4][2];                 // chunk B-frag buffer B

#define BLOAD(DST, KC)                                                       \
    if ((KC) < NK) {                                                         \
        const __bf16* g = bbase + (size_t)(KC) * CHUNK_ELEMS;                \
        _Pragma("unroll")                                                    \
        for (int s = 0; s < 4; ++s) {                                        \
            DST[s][0] = *(const bf16x8*)(g + s * 4096);                      \
            DST[s][1] = *(const bf16x8*)(g + s * 4096 + 512);                \
        }                                                                    \
    }

// J = input within this thread's float4; input-in-super = pg*4 + J
#define FEATW(NB, J, XS)                                                     \
    *(bf16x8*)(&Alds[NB][(pg * 4 + (J)) * APAGE + m * 8]) = featurize(XS)

// chunk CC (0..3) of current super from Alds[CB]; B frags in CUR
#define CHUNK_COMPUTE(CB, CC, CUR)                                           \
    _Pragma("unroll")                                                        \
    for (int s4 = 0; s4 < 4; ++s4) {                                         \
        bf16x8 af = *(const bf16x8*)(&Alds[CB][((CC) * 8 + 2 * s4 + h) * APAGE + mr * 256 + l31 * 8]); \
        acc[0] = __builtin_amdgcn_mfma_f32_32x32x16_bf16(af, CUR[s4][0], acc[0], 0, 0, 0); \
        acc[1] = __builtin_amdgcn_mfma_f32_32x32x16_bf16(af, CUR[s4][1], acc[1], 0, 0, 0); \
    }

    // ---- prologue: featurize super 0 into buf 0, B chunk 0, x for super 1 ----
    float4 xq = *(const float4*)(xptr);
    BLOAD(bfr0, 0);
    float4 xa = *(const float4*)(xptr + 32);
    float4 xb = xa;                    // init to silence uninitialized use
    FEATW(0, 0, xq.x); FEATW(0, 1, xq.y); FEATW(0, 2, xq.z); FEATW(0, 3, xq.w);
    BARRIER();

    // One super-step: compute 4 chunks from Alds[CB] + B reg dbuf; featurize
    // super S+1 from XC into Alds[NB], interleaved between chunk computes;
    // prefetch x for super S+2 into XN. Single barrier at the end.
#define SUPER_STEP(S, CB, NB, XC, XN)                                        \
    {                                                                        \
        const bool dofeat = (S) + 1 < NSUP;                                  \
        BLOAD(bfr1, (S) * 4 + 1);                                            \
        if (dofeat) { FEATW(NB, 0, XC.x); }                                  \
        CHUNK_COMPUTE(CB, 0, bfr0);                                          \
        BLOAD(bfr0, (S) * 4 + 2);                                            \
        if (dofeat) { FEATW(NB, 1, XC.y); }                                  \
        CHUNK_COMPUTE(CB, 1, bfr1);                                          \
        BLOAD(bfr1, (S) * 4 + 3);                                            \
        if (dofeat) { FEATW(NB, 2, XC.z); }                                  \
        CHUNK_COMPUTE(CB, 2, bfr0);                                          \
        BLOAD(bfr0, (S) * 4 + 4);                                            \
        if (dofeat) { FEATW(NB, 3, XC.w); }                                  \
        if ((S) + 2 < NSUP) {                                                \
            XN = *(const float4*)(xptr + ((S) + 2) * 32);                    \
        }                                                                    \
        CHUNK_COMPUTE(CB, 3, bfr1);                                          \
        BARRIER();                                                           \
    }

    for (int sp = 0; sp < NSUP; sp += 2) {
        SUPER_STEP(sp,     0, 1, xa, xb);
        SUPER_STEP(sp + 1, 1, 0, xb, xa);
    }
#undef SUPER_STEP
#undef CHUNK_COMPUTE
#undef FEATW
#undef BLOAD

    // ---- epilogue: 32x32 C/D col=lane&31, row=(reg&3)+8*(reg>>2)+4*h (R7-validated) ----
    #pragma unroll
    for (int ni = 0; ni < 2; ++ni) {
        #pragma unroll
        for (int r = 0; r < 16; ++r) {
            int rl  = (r & 3) + 8 * (r >> 2) + 4 * h;
            int row = bm * BM + mr * 32 + rl;
            out[(size_t)row * OUT_DIM + c * 64 + ni * 32 + l31] = acc[ni][r];
        }
    }
}

// ---------------------------------------------------------------------------
extern "C" void kernel_launch(void* const* d_in, const int* in_sizes, int n_in,
                              void* d_out, int out_size, void* d_ws, size_t ws_size,
                              hipStream_t stream) {
    const float* x = (const float*)d_in[0];          // [16,2048,256] fp32
    const float* C = (const float*)d_in[1];          // [256,256,8]  fp32
    float* out = (float*)d_out;                      // [16,2048,256] fp32
    __bf16* Bt = (__bf16*)d_ws;                      // paged [32][16384] bf16, 1 MB

    reorder_coeffs<<<dim3((INPUT_DIM * OUT_DIM) / 256), dim3(256), 0, stream>>>(C, Bt);
    hermite_mfma<<<dim3(NROWS / BM), dim3(512), 0, stream>>>(x, Bt, out);
}

// Round 4
// 125.032 us; speedup vs baseline: 1.0882x; 1.0882x over previous
//
#include <hip/hip_runtime.h>
#include <hip/hip_bf16.h>
#include <math.h>

#define INPUT_DIM 256
#define OUT_DIM   256
#define NDEG      8                    // degree+1
#define KTOT      (INPUT_DIM * NDEG)   // 2048
#define NROWS     (16 * 2048)          // 32768

#define BM  64                         // block rows (featurize exactly once globally)
#define BK  64                         // 8 inputs * 8 degrees per K-chunk
#define NK  (KTOT / BK)                // 32
#define SUPER 4                        // chunks per super-step (barrier granularity)
#define NSUP  (NK / SUPER)             // 8
#define CHUNK_ELEMS 16384              // full-width B chunk: 256 o * 64 k
#define APAGE 512                      // A page: 64 rows * 8 deg (one input)
#define ACHUNK (8 * APAGE)             // 4096 elems = 8 KB

typedef __bf16 bf16x8 __attribute__((ext_vector_type(8)));
typedef float  f32x16 __attribute__((ext_vector_type(16)));

// ---------------------------------------------------------------------------
// Kernel 1: reorder coeffs C[i][o][d] (fp32) -> B pages (bf16). Unchanged R9
// layout (row-tile independent): frag(kc,s,c,ni) at
//   kc*16384 + (s*4+c)*1024 + ni*512 + h*256 + l31*8 + d
// ---------------------------------------------------------------------------
__global__ __launch_bounds__(256) void reorder_coeffs(const float* __restrict__ C,
                                                      __bf16* __restrict__ Bt) {
    int g = blockIdx.x * 256 + threadIdx.x;   // 65536 = 256 i * 256 o
    int i = g >> 8;
    int o = g & 255;
    const float4* src = (const float4*)(C + (size_t)i * (OUT_DIM * NDEG) + o * NDEG);
    float4 a = src[0];
    float4 b = src[1];
    bf16x8 v;
    v[0] = (__bf16)a.x; v[1] = (__bf16)a.y; v[2] = (__bf16)a.z; v[3] = (__bf16)a.w;
    v[4] = (__bf16)b.x; v[5] = (__bf16)b.y; v[6] = (__bf16)b.z; v[7] = (__bf16)b.w;
    int kc = i >> 3;
    int p  = i & 7;
    int s  = p >> 1;
    int hh = p & 1;
    int cc = o >> 6;
    int ni = (o >> 5) & 1;
    int l31 = o & 31;
    size_t dst = (size_t)kc * CHUNK_ELEMS + (s * 4 + cc) * 1024 + ni * 512 + hh * 256 + l31 * 8;
    *(bf16x8*)(Bt + dst) = v;   // 16B-aligned
}

// tanh + physicists' Hermite recurrence -> 8 degrees as bf16x8
__device__ __forceinline__ bf16x8 featurize(float xs) {
    float e = __expf(2.0f * xs);            // tanh(x)=1-2/(e^{2x}+1), robust all x
    float t = 1.0f - 2.0f / (e + 1.0f);
    bf16x8 v;
    float hm2 = 1.0f;                       // H_0
    float hm1 = 2.0f * t;                   // H_1
    v[0] = (__bf16)hm2;
    v[1] = (__bf16)hm1;
    #pragma unroll
    for (int d = 2; d < 8; ++d) {
        float h = 2.0f * t * hm1 - 2.0f * (float)(d - 1) * hm2;
        v[d] = (__bf16)h;
        hm2 = hm1; hm1 = h;
    }
    return v;
}

// lgkm-only barrier: each wave's own LDS writes/reads complete (lgkmcnt(0))
// before it signals -- full producer/consumer requirement for the Alds dbuf.
// B/x prefetch loads target registers and carry compiler vmcnt waits at use
// sites; they legally stay in flight across the barrier.
#define BARRIER() do {                                             \
    asm volatile("s_waitcnt lgkmcnt(0)" ::: "memory");             \
    __builtin_amdgcn_s_barrier();                                  \
    asm volatile("" ::: "memory");                                 \
} while (0)

// ---------------------------------------------------------------------------
// Kernel 2 (Round 13): R12 architecture, allocator un-choked.
//  R12 post-mortem: __launch_bounds__(512,4) capped the unified reg file at
//  128/wave -> 64 ARCH VGPRs (VGPR_Count=64), spilling the B reg dbuf:
//  WRITE_SIZE 32.8->60.4 MB (scratch), dur 45->70 us. The 2-blocks/CU
//  mechanism (independent barrier groups -> phase decorrelation -> m114
//  MFMA/VALU/LDS overlap) was never actually tested.
//  Fix: __launch_bounds__(512,2) (cap 256 regs -> no spill). Residency comes
//  from actual fit: LDS 64 KB x2 <= 160 KB; regs ~80 arch + 32 acc <= 128
//  -> 4 waves/SIMD = 2 blocks/CU (m69 steps). Spill tripwire: WRITE_SIZE
//  must return to 32768 KB.
// Block 512 thr / 8 waves (2 mr x 4 c), tile 64x256, wave tile 32x64, grid 512.
// ---------------------------------------------------------------------------
__global__ __launch_bounds__(512, 2) void hermite_mfma(const float* __restrict__ x,
                                                       const __bf16* __restrict__ Bt,
                                                       float* __restrict__ out) {
    // [buf][(input-in-super)*512 + m*8]; input-in-super = chunk cc*8 + page j
    __shared__ __align__(16) __bf16 Alds[2][SUPER * ACHUNK];   // 64 KB

    const int tid  = threadIdx.x;
    const int bm   = blockIdx.x;       // 0..511
    const int wave = tid >> 6;         // 0..7
    const int mr   = wave >> 2;        // 0..1 : row half (32 rows each)
    const int c    = wave & 3;         // 0..3 : column slice
    const int lane = tid & 63;
    const int l31  = lane & 31;
    const int h    = lane >> 5;

    // Featurize mapping: thread (m = tid&63, pg = tid>>6) covers row m,
    // inputs sup*32 + pg*4 + {0..3} (one float4). Exactly-once globally.
    const int m  = tid & 63;
    const int pg = tid >> 6;           // 0..7
    const float* xptr = x + (size_t)(bm * BM + m) * INPUT_DIM + pg * 4;

    // B pages for column slice c: frag(kc,s,ni) at Bt + kc*16384 + (s*4+c)*1024
    //   + ni*512 + lane*8
    const __bf16* bbase = Bt + (size_t)c * 1024 + lane * 8;

    f32x16 acc[2] = {};
    bf16x8 bfr0[4][2];                 // chunk B-frag buffer A (static names)
    bf16x8 bfr1[4][2];                 // chunk B-frag buffer B

#define BLOAD(DST, KC)                                                       \
    if ((KC) < NK) {                                                         \
        const __bf16* g = bbase + (size_t)(KC) * CHUNK_ELEMS;                \
        _Pragma("unroll")                                                    \
        for (int s = 0; s < 4; ++s) {                                        \
            DST[s][0] = *(const bf16x8*)(g + s * 4096);                      \
            DST[s][1] = *(const bf16x8*)(g + s * 4096 + 512);                \
        }                                                                    \
    }

// J = input within this thread's float4; input-in-super = pg*4 + J
#define FEATW(NB, J, XS)                                                     \
    *(bf16x8*)(&Alds[NB][(pg * 4 + (J)) * APAGE + m * 8]) = featurize(XS)

// chunk CC (0..3) of current super from Alds[CB]; B frags in CUR
#define CHUNK_COMPUTE(CB, CC, CUR)                                           \
    _Pragma("unroll")                                                        \
    for (int s4 = 0; s4 < 4; ++s4) {                                         \
        bf16x8 af = *(const bf16x8*)(&Alds[CB][((CC) * 8 + 2 * s4 + h) * APAGE + mr * 256 + l31 * 8]); \
        acc[0] = __builtin_amdgcn_mfma_f32_32x32x16_bf16(af, CUR[s4][0], acc[0], 0, 0, 0); \
        acc[1] = __builtin_amdgcn_mfma_f32_32x32x16_bf16(af, CUR[s4][1], acc[1], 0, 0, 0); \
    }

    // ---- prologue: featurize super 0 into buf 0, B chunk 0, x for super 1 ----
    float4 xq = *(const float4*)(xptr);
    BLOAD(bfr0, 0);
    float4 xa = *(const float4*)(xptr + 32);
    float4 xb = xa;                    // init to silence uninitialized use
    FEATW(0, 0, xq.x); FEATW(0, 1, xq.y); FEATW(0, 2, xq.z); FEATW(0, 3, xq.w);
    BARRIER();

    // One super-step: compute 4 chunks from Alds[CB] + B reg dbuf; featurize
    // super S+1 from XC into Alds[NB], interleaved between chunk computes;
    // prefetch x for super S+2 into XN. Single barrier at the end.
#define SUPER_STEP(S, CB, NB, XC, XN)                                        \
    {                                                                        \
        const bool dofeat = (S) + 1 < NSUP;                                  \
        BLOAD(bfr1, (S) * 4 + 1);                                            \
        if (dofeat) { FEATW(NB, 0, XC.x); }                                  \
        CHUNK_COMPUTE(CB, 0, bfr0);                                          \
        BLOAD(bfr0, (S) * 4 + 2);                                            \
        if (dofeat) { FEATW(NB, 1, XC.y); }                                  \
        CHUNK_COMPUTE(CB, 1, bfr1);                                          \
        BLOAD(bfr1, (S) * 4 + 3);                                            \
        if (dofeat) { FEATW(NB, 2, XC.z); }                                  \
        CHUNK_COMPUTE(CB, 2, bfr0);                                          \
        BLOAD(bfr0, (S) * 4 + 4);                                            \
        if (dofeat) { FEATW(NB, 3, XC.w); }                                  \
        if ((S) + 2 < NSUP) {                                                \
            XN = *(const float4*)(xptr + ((S) + 2) * 32);                    \
        }                                                                    \
        CHUNK_COMPUTE(CB, 3, bfr1);                                          \
        BARRIER();                                                           \
    }

    for (int sp = 0; sp < NSUP; sp += 2) {
        SUPER_STEP(sp,     0, 1, xa, xb);
        SUPER_STEP(sp + 1, 1, 0, xb, xa);
    }
#undef SUPER_STEP
#undef CHUNK_COMPUTE
#undef FEATW
#undef BLOAD

    // ---- epilogue: 32x32 C/D col=lane&31, row=(reg&3)+8*(reg>>2)+4*h (R7-validated) ----
    #pragma unroll
    for (int ni = 0; ni < 2; ++ni) {
        #pragma unroll
        for (int r = 0; r < 16; ++r) {
            int rl  = (r & 3) + 8 * (r >> 2) + 4 * h;
            int row = bm * BM + mr * 32 + rl;
            out[(size_t)row * OUT_DIM + c * 64 + ni * 32 + l31] = acc[ni][r];
        }
    }
}

// ---------------------------------------------------------------------------
extern "C" void kernel_launch(void* const* d_in, const int* in_sizes, int n_in,
                              void* d_out, int out_size, void* d_ws, size_t ws_size,
                              hipStream_t stream) {
    const float* x = (const float*)d_in[0];          // [16,2048,256] fp32
    const float* C = (const float*)d_in[1];          // [256,256,8]  fp32
    float* out = (float*)d_out;                      // [16,2048,256] fp32
    __bf16* Bt = (__bf16*)d_ws;                      // paged [32][16384] bf16, 1 MB

    reorder_coeffs<<<dim3((INPUT_DIM * OUT_DIM) / 256), dim3(256), 0, stream>>>(C, Bt);
    hermite_mfma<<<dim3(NROWS / BM), dim3(512), 0, stream>>>(x, Bt, out);
}